// Round 1
// 1196.525 us; speedup vs baseline: 1.0887x; 1.0887x over previous
//
#include <hip/hip_runtime.h>
#include <hip/hip_bf16.h>

// Problem: B=2, S=2048, D=1024, H=16, DK=64.  All I/O is FLOAT32.
#define B_DIM 2
#define S_DIM 2048
#define D_DIM 1024
#define H_DIM 16
#define DK_DIM 64

typedef __attribute__((ext_vector_type(8))) short short8;   // bf16x8 MFMA fragment
typedef __attribute__((ext_vector_type(4))) float floatx4;  // MFMA accumulator

__device__ __forceinline__ unsigned short f2bf(float f) {
    unsigned u = __builtin_bit_cast(unsigned, f);
    u += 0x7fff + ((u >> 16) & 1);   // RTN-even; inputs finite
    return (unsigned short)(u >> 16);
}

#define GLDS16(g, l) __builtin_amdgcn_global_load_lds( \
    (const __attribute__((address_space(1))) void*)(g), \
    (__attribute__((address_space(3))) void*)(l), 16, 0, 0)

// Stage ROWS x 64 bf16 tile (dense row-major LDS) from bf16 global rows of
// stride ld elements, via async global_load_lds (16B/lane, wave-uniform dest).
template <int ROWS>
__device__ __forceinline__ void stage_tile(const unsigned short* __restrict__ src, int ld,
                                           short* lds, int tid) {
#pragma unroll
    for (int r = 0; r < ROWS / 32; ++r) {
        int t = r * 256 + tid;                         // linear 16B-chunk id
        const unsigned short* g = src + (size_t)(t >> 3) * ld + ((t & 7) << 3);
        short* dst = lds + ((size_t)(r * 256 + (tid >> 6) * 64) << 3);
        GLDS16(g, dst);
    }
}

// Stage ROWS x 64 fp32 tile from global (stride ld) into dense bf16 LDS tile,
// converting on the way (float4 load -> 4x f2bf -> 8B ds_write).
template <int ROWS>
__device__ __forceinline__ void stage_cvt(const float* __restrict__ src, int ld,
                                          short* lds, int tid) {
#pragma unroll
    for (int i = 0; i < ROWS / 16; ++i) {
        int f = i * 256 + tid;                         // float4 id
        int row = f >> 4, c4 = (f & 15) << 2;
        float4 v = *(const float4*)(src + (size_t)row * ld + c4);
        union { ushort4 u; uint2 d; } p;
        p.u.x = f2bf(v.x); p.u.y = f2bf(v.y); p.u.z = f2bf(v.z); p.u.w = f2bf(v.w);
        *(uint2*)&lds[row * 64 + c4] = p.d;
    }
}

// ---------------------------------------------------------------------------
// K1 / K4: C[M][N] = A[M][K] * W[N][K]^T + bias.  A is fp32 (abf16=0) or bf16
// (abf16=1, staged via global_load_lds).  mode 0: bf16 row-major out.
// mode 1: bf16 per-head transposed vT[(b*16+h)*64+dk][s]. mode 2: fp32 out.
// ---------------------------------------------------------------------------
struct GemmBatchF {
    const float* A[3];
    const float* W[3];
    const float* bias[3];
    void* C[3];
    int mode[3];
    int abf16[3];
};

__global__ __launch_bounds__(256) void gemm_f32bt(GemmBatchF p, int N, int K) {
    __shared__ short At[128 * 64];
    __shared__ short Bt[128 * 64];
    int z = blockIdx.z;
    const float* A = p.A[z];
    const float* W = p.W[z];
    const float* bias = p.bias[z];
    void* Cv = p.C[z];
    int mode = p.mode[z];
    int abf = p.abf16[z];

    int tid = threadIdx.x;
    int wave = tid >> 6, lane = tid & 63;
    int l15 = lane & 15, quad = lane >> 4;
    int bn = blockIdx.x, bm = blockIdx.y;
    const float* Ab = A + (size_t)bm * 128 * K;
    const unsigned short* Abh = (const unsigned short*)A + (size_t)bm * 128 * K;
    const float* Wb = W + (size_t)bn * 128 * K;
    int wm = (wave >> 1) * 64, wn = (wave & 1) * 64;

    floatx4 acc[4][4] = {};
    for (int k0 = 0; k0 < K; k0 += 64) {
        __syncthreads();   // previous iteration's LDS reads done
        if (abf) stage_tile<128>(Abh + k0, K, At, tid);
        else     stage_cvt<128>(Ab + k0, K, At, tid);
        stage_cvt<128>(Wb + k0, K, Bt, tid);
        __syncthreads();
#pragma unroll
        for (int kk = 0; kk < 2; ++kk) {
            short8 af[4], bf[4];
#pragma unroll
            for (int i = 0; i < 4; ++i)
                af[i] = *(const short8*)&At[(wm + i * 16 + l15) * 64 + kk * 32 + quad * 8];
#pragma unroll
            for (int j = 0; j < 4; ++j)
                bf[j] = *(const short8*)&Bt[(wn + j * 16 + l15) * 64 + kk * 32 + quad * 8];
#pragma unroll
            for (int i = 0; i < 4; ++i)
#pragma unroll
                for (int j = 0; j < 4; ++j)
                    acc[i][j] = __builtin_amdgcn_mfma_f32_16x16x32_bf16(af[i], bf[j], acc[i][j], 0, 0, 0);
        }
    }

    int row0 = bm * 128 + wm + quad * 4;
    int col0 = bn * 128 + wn + l15;
    if (mode == 0) {
        unsigned short* C = (unsigned short*)Cv;
#pragma unroll
        for (int j = 0; j < 4; ++j) {
            int col = col0 + j * 16;
            float bc = bias[col];
#pragma unroll
            for (int i = 0; i < 4; ++i) {
                int row = row0 + i * 16;
#pragma unroll
                for (int r = 0; r < 4; ++r)
                    C[(size_t)(row + r) * N + col] = f2bf(acc[i][j][r] + bc);
            }
        }
    } else if (mode == 1) {
        unsigned short* C = (unsigned short*)Cv;
#pragma unroll
        for (int j = 0; j < 4; ++j) {
            int col = col0 + j * 16;
            float bc = bias[col];
            int h = col >> 6, dk = col & 63;
#pragma unroll
            for (int i = 0; i < 4; ++i) {
                int row = row0 + i * 16;
                int b = row >> 11, s = row & 2047;
                size_t base = (((size_t)(b * 16 + h) * 64 + dk) << 11) + s;
                uint2 pk;
                pk.x = (unsigned)f2bf(acc[i][j][0] + bc) | ((unsigned)f2bf(acc[i][j][1] + bc) << 16);
                pk.y = (unsigned)f2bf(acc[i][j][2] + bc) | ((unsigned)f2bf(acc[i][j][3] + bc) << 16);
                *(uint2*)(C + base) = pk;
            }
        }
    } else {
        float* C = (float*)Cv;
#pragma unroll
        for (int j = 0; j < 4; ++j) {
            int col = col0 + j * 16;
            float bc = bias[col];
#pragma unroll
            for (int i = 0; i < 4; ++i) {
                int row = row0 + i * 16;
#pragma unroll
                for (int r = 0; r < 4; ++r)
                    C[(size_t)(row + r) * N + col] = acc[i][j][r] + bc;
            }
        }
    }
}

// ---------------------------------------------------------------------------
// K2 fused: scores = QK^T/8 (bf16 MFMA), row softmax, fp32 weights to wout,
// AND ctx = P @ V fused into sweep B (PV via per-wave LDS transpose of P).
// Barrier-free: Q/K/V fragments loaded per-lane from global (L1/L2-served);
// the only LDS is a per-wave-private 16x64 P-transpose tile (wave-local
// lgkmcnt ordering, no __syncthreads anywhere).
// ctx written bf16 to ctx_bf; caller aliases ctx_bf onto q_ws: each block
// reads exactly its own 64x64 Q tile into registers at start and writes ctx
// to the same addresses at the end (per-wave bijection -> race-free under
// any dispatch order).
// ---------------------------------------------------------------------------
__device__ __forceinline__ int pswz(int row, int col) {
    // row-major [16][64] shorts, XOR-swizzle on 8-short granularity:
    // conflict-free ds_read_b128 of 8 consecutive k for row=l15.
    return (row << 6) + ((((col >> 3) ^ row) & 7) << 3) + (col & 7);
}

__global__ __launch_bounds__(256) void attn_fused(const unsigned short* q_ws,
                                                  const unsigned short* __restrict__ k_ws,
                                                  const unsigned short* __restrict__ vT,
                                                  float* __restrict__ wout,
                                                  unsigned short* ctx_bf) {
    __shared__ short Pt[4 * 16 * 64];   // per-wave private 2KB transpose tiles
    int tid = threadIdx.x;
    int wave = tid >> 6, lane = tid & 63;
    int l15 = lane & 15, quad = lane >> 4;
    int bh = blockIdx.y;
    int b = bh >> 4, h = bh & 15;
    int q0 = blockIdx.x * 64;

    // Q fragments straight from global (consumed into registers once)
    const unsigned short* Qp =
        q_ws + (size_t)(b * S_DIM + q0 + wave * 16 + l15) * D_DIM + h * 64 + quad * 8;
    short8 a0 = *(const short8*)Qp;
    short8 a1 = *(const short8*)(Qp + 32);

    const unsigned short* Kb = k_ws + (size_t)b * S_DIM * D_DIM + h * 64;
    const unsigned short* Vb = vT + (size_t)bh * 64 * S_DIM;

    const float SC = 0.18033688011112042f;  // log2(e)/sqrt(64)
    float m[4], l[4];
#pragma unroll
    for (int r = 0; r < 4; ++r) { m[r] = -__builtin_inff(); l[r] = 0.f; }

    // Sweep A: online max / denominator (no LDS, no barriers)
    for (int kt = 0; kt < 32; ++kt) {
        const unsigned short* Kt = Kb + (size_t)(kt * 64) * D_DIM;
        floatx4 acc[4] = {};
#pragma unroll
        for (int j = 0; j < 4; ++j) {
            const unsigned short* kp = Kt + (size_t)(j * 16 + l15) * D_DIM + quad * 8;
            short8 b0 = *(const short8*)kp;
            short8 b1 = *(const short8*)(kp + 32);
            acc[j] = __builtin_amdgcn_mfma_f32_16x16x32_bf16(a0, b0, acc[j], 0, 0, 0);
            acc[j] = __builtin_amdgcn_mfma_f32_16x16x32_bf16(a1, b1, acc[j], 0, 0, 0);
        }
        float v[4][4];
#pragma unroll
        for (int j = 0; j < 4; ++j)
#pragma unroll
            for (int r = 0; r < 4; ++r) v[j][r] = acc[j][r] * SC;
        float tmax[4];
#pragma unroll
        for (int r = 0; r < 4; ++r)
            tmax[r] = fmaxf(fmaxf(v[0][r], v[1][r]), fmaxf(v[2][r], v[3][r]));
#pragma unroll
        for (int off = 1; off < 16; off <<= 1)
#pragma unroll
            for (int r = 0; r < 4; ++r)
                tmax[r] = fmaxf(tmax[r], __shfl_xor(tmax[r], off));
        float alpha[4], ps[4];
#pragma unroll
        for (int r = 0; r < 4; ++r) {
            float mn = fmaxf(m[r], tmax[r]);
            alpha[r] = exp2f(m[r] - mn);
            m[r] = mn;
            ps[r] = exp2f(v[0][r] - mn) + exp2f(v[1][r] - mn) +
                    exp2f(v[2][r] - mn) + exp2f(v[3][r] - mn);
        }
#pragma unroll
        for (int off = 1; off < 16; off <<= 1)
#pragma unroll
            for (int r = 0; r < 4; ++r)
                ps[r] += __shfl_xor(ps[r], off);
#pragma unroll
        for (int r = 0; r < 4; ++r) l[r] = l[r] * alpha[r] + ps[r];
    }
    float rl[4];
#pragma unroll
    for (int r = 0; r < 4; ++r) rl[r] = 1.0f / l[r];

    // Sweep B: recompute scores, write normalized fp32 weights, fused PV
    short* Pw = &Pt[wave * 16 * 64];
    floatx4 cacc[4] = {};
    float* wrow = wout + ((size_t)bh * S_DIM + q0 + wave * 16 + quad * 4) * (size_t)S_DIM;

    for (int kt = 0; kt < 32; ++kt) {
        const unsigned short* Kt = Kb + (size_t)(kt * 64) * D_DIM;
        floatx4 acc[4] = {};
#pragma unroll
        for (int j = 0; j < 4; ++j) {
            const unsigned short* kp = Kt + (size_t)(j * 16 + l15) * D_DIM + quad * 8;
            short8 b0 = *(const short8*)kp;
            short8 b1 = *(const short8*)(kp + 32);
            acc[j] = __builtin_amdgcn_mfma_f32_16x16x32_bf16(a0, b0, acc[j], 0, 0, 0);
            acc[j] = __builtin_amdgcn_mfma_f32_16x16x32_bf16(a1, b1, acc[j], 0, 0, 0);
        }
#pragma unroll
        for (int j = 0; j < 4; ++j) {
            int colo = kt * 64 + j * 16 + l15;
#pragma unroll
            for (int r = 0; r < 4; ++r) {
                float w = exp2f(acc[j][r] * SC - m[r]) * rl[r];
                wrow[(size_t)r * S_DIM + colo] = w;                     // output 1
                Pw[pswz(quad * 4 + r, j * 16 + l15)] = (short)f2bf(w);  // P -> LDS
            }
        }
        // wave-local RAW: drain ds_writes, pin MFMA below (rule #18)
        asm volatile("s_waitcnt lgkmcnt(0)" ::: "memory");
        __builtin_amdgcn_sched_barrier(0);
#pragma unroll
        for (int kk = 0; kk < 2; ++kk) {
            short8 ap = *(const short8*)&Pw[pswz(l15, kk * 32 + quad * 8)];
#pragma unroll
            for (int j = 0; j < 4; ++j) {
                short8 bv = *(const short8*)&Vb[(size_t)(j * 16 + l15) * S_DIM +
                                                kt * 64 + kk * 32 + quad * 8];
                cacc[j] = __builtin_amdgcn_mfma_f32_16x16x32_bf16(ap, bv, cacc[j], 0, 0, 0);
            }
        }
    }

    // ctx (bf16) over this block's own Q tile addresses (safe aliasing)
    unsigned short* cb =
        ctx_bf + (size_t)(b * S_DIM + q0 + wave * 16 + quad * 4) * D_DIM + h * 64;
#pragma unroll
    for (int j = 0; j < 4; ++j)
#pragma unroll
        for (int r = 0; r < 4; ++r)
            cb[(size_t)r * D_DIM + j * 16 + l15] = f2bf(cacc[j][r]);
}

// ---------------------------------------------------------------------------
extern "C" void kernel_launch(void* const* d_in, const int* in_sizes, int n_in,
                              void* d_out, int out_size, void* d_ws, size_t ws_size,
                              hipStream_t stream) {
    const float* query = (const float*)d_in[0];
    const float* key_  = (const float*)d_in[1];
    const float* value = (const float*)d_in[2];
    const float* W_q = (const float*)d_in[3];
    const float* b_q = (const float*)d_in[4];
    const float* W_k = (const float*)d_in[5];
    const float* b_k = (const float*)d_in[6];
    const float* W_v = (const float*)d_in[7];
    const float* b_v = (const float*)d_in[8];
    const float* W_o = (const float*)d_in[9];
    const float* b_o = (const float*)d_in[10];

    float* out  = (float*)d_out;                       // [4096][1024] fp32
    float* wout = out + (size_t)4096 * 1024;           // [32][2048][2048] fp32

    // ws layout (24 MB peak):
    //   [0,8)MB  q_ws bf16  (K1 -> K2)  -- K2 overwrites in place with ctx bf16
    //   [8,16)MB k_ws bf16  (K1 -> K2)
    //   [16,24)MB vT bf16   (K1 -> K2 PV)
    unsigned short* q_ws = (unsigned short*)d_ws;
    unsigned short* k_ws = q_ws + (size_t)4096 * 1024;
    unsigned short* vT   = k_ws + (size_t)4096 * 1024;
    unsigned short* ctx_bf = q_ws;                     // in-place alias (see K2)

    // K1: QKV projections (z=0:Q->q_ws, 1:K->k_ws, 2:V->vT transposed)
    GemmBatchF p1;
    p1.A[0] = query; p1.A[1] = key_; p1.A[2] = value;
    p1.W[0] = W_q;   p1.W[1] = W_k;  p1.W[2] = W_v;
    p1.bias[0] = b_q; p1.bias[1] = b_k; p1.bias[2] = b_v;
    p1.C[0] = q_ws;  p1.C[1] = k_ws; p1.C[2] = vT;
    p1.mode[0] = 0;  p1.mode[1] = 0; p1.mode[2] = 1;
    p1.abf16[0] = 0; p1.abf16[1] = 0; p1.abf16[2] = 0;
    gemm_f32bt<<<dim3(8, 32, 3), 256, 0, stream>>>(p1, 1024, 1024);

    // K2: fused scores + softmax + weights-write + PV (ctx bf16 in place)
    attn_fused<<<dim3(32, 32), 256, 0, stream>>>(q_ws, k_ws, vT, wout, ctx_bf);

    // K4: output projection (output 0, fp32), A staged as bf16 via GLDS
    GemmBatchF p4;
    for (int i = 0; i < 3; ++i) {
        p4.A[i] = (const float*)ctx_bf; p4.W[i] = W_o; p4.bias[i] = b_o;
        p4.C[i] = out; p4.mode[i] = 2; p4.abf16[i] = 1;
    }
    gemm_f32bt<<<dim3(8, 32, 1), 256, 0, stream>>>(p4, 1024, 1024);
}